// Round 14
// baseline (285.219 us; speedup 1.0000x reference)
//
#include <hip/hip_runtime.h>

#define M_DIM 16384
#define N_DIM 1024
#define K_DIM 4096

#define BM 128
#define BN 128
#define BK 32
#define NT (K_DIM / BK)

typedef __attribute__((ext_vector_type(4))) float f32x4;
typedef __attribute__((ext_vector_type(8))) short bf16x8;
typedef __attribute__((ext_vector_type(8))) unsigned short u16x8;

static __device__ __forceinline__ short f2bf(float f) {
  union { __bf16 h; short s; } u;
  u.h = (__bf16)f;   // RNE; pairs pack into v_cvt_pk_bf16_f32
  return u.s;
}

static __device__ __forceinline__ void load_lds16(const void* g, void* l) {
  __builtin_amdgcn_global_load_lds(
      (const __attribute__((address_space(1))) void*)g,
      (__attribute__((address_space(3))) void*)l, 16, 0, 0);
}

// ---------- prepass: WbT[n][k] = bf16(sign(W[k][n])) ----------
__global__ __launch_bounds__(256) void wsign_transpose(
    const float* __restrict__ W, unsigned short* __restrict__ WbT) {
  __shared__ unsigned short tile[64][72];
  const int t  = (int)threadIdx.x;
  const int k0 = (int)(blockIdx.x >> 4) * 64;
  const int n0 = (int)(blockIdx.x & 15) * 64;
#pragma unroll
  for (int p = 0; p < 4; ++p) {
    const int r = p * 16 + (t >> 4);
    const int c = (t & 15) * 4;
    const float* src = W + (size_t)(k0 + r) * N_DIM + n0 + c;
#pragma unroll
    for (int j = 0; j < 4; ++j) {
      const float w = src[j];
      tile[r][c + j] = (w > 0.f) ? (unsigned short)0x3F80u
                                 : ((w < 0.f) ? (unsigned short)0xBF80u
                                              : (unsigned short)0u);
    }
  }
  __syncthreads();
  const int n  = t >> 2;
  const int kg = (t & 3) * 16;
  u16x8 o0, o1;
#pragma unroll
  for (int j = 0; j < 8; ++j) o0[j] = tile[kg + j][n];
#pragma unroll
  for (int j = 0; j < 8; ++j) o1[j] = tile[kg + 8 + j][n];
  unsigned short* dst = WbT + (size_t)(n0 + n) * K_DIM + k0 + kg;
  *(u16x8*)dst       = o0;
  *(u16x8*)(dst + 8) = o1;
}

// ---------- main GEMM: 128x128, BK=32, 4 waves, 3 blocks/CU ----------
// Occupancy play: 32 KiB LDS + VGPR<=170 -> 3 independent blocks per CU
// (12 waves/CU). Simple m97-proven 2-barrier loop; inter-block wave
// independence covers barrier drains (m114 mechanism). A: fused fp32->bf16
// reg-staged; B: global_load_lds w16, inverse-swizzled source (rule #21).
// Granule swizzle g ^= (r&3)^((r>>2)&3): worst 2-way alias (free, m136).
__global__ __launch_bounds__(256, 3) void gemm_occ(
    const float* __restrict__ X, const unsigned short* __restrict__ WbT,
    const float* __restrict__ bias, float* __restrict__ Z) {
  __shared__ __align__(16) unsigned short As[2][BM * BK];  // 16 KiB
  __shared__ __align__(16) unsigned short Bs[2][BN * BK];  // 16 KiB

  const int t   = (int)threadIdx.x;
  const int l   = t & 63;
  const int wid = t >> 6;
  const int wm  = wid >> 1;  // 0..1
  const int wn  = wid & 1;   // 0..1

  // XCD-bijective swizzle: 1024 blocks % 8 == 0; n-fastest within XCD
  const int bid = (int)blockIdx.x;
  const int swz = (bid & 7) * 128 + (bid >> 3);
  const int m0  = (swz >> 3) * BM;   // 128 m-tiles
  const int n0  = (swz & 7) * BN;    // 8 n-tiles

  // fragment read offsets: granule p = q ^ f(r), f(r) = (r&3)^((r>>2)&3)
  const int axx   = ((((l >> 4) ^ (l & 3) ^ ((l >> 2) & 3)) & 3)) << 3;
  const int abase = (wm * 64 + (l & 15)) * BK;
  const int bbase = (wn * 64 + (l & 15)) * BK;

  // A staging: thread t -> row r = t>>1 (64B of fp32), half h = t&1
  const int rA = t >> 1, hA = t & 1;
  const float* srcA = X + (size_t)(m0 + rA) * K_DIM + hA * 16;
  const int fr   = (rA & 3) ^ ((rA >> 2) & 3);
  const int g0   = (2 * hA) ^ fr;          // physical granule of first u16x8
  const int adst0 = rA * BK + ((g0 & 3) << 3);
  const int adst1 = rA * BK + (((g0 ^ 1) & 3) << 3);

  // B staging: 2 chunks/thread; linear dest, inverse-swizzled source
  const unsigned short* bsrc[2];
  int bdst[2];
#pragma unroll
  for (int i = 0; i < 2; ++i) {
    const int c = i * 256 + t;
    const int n = c >> 2, p = c & 3;
    const int q = p ^ ((n & 3) ^ ((n >> 2) & 3));
    bsrc[i] = WbT + (size_t)(n0 + n) * K_DIM + q * 8;
    bdst[i] = c * 8;
  }

  f32x4 acc[4][4] = {};   // 64 acc regs
  f32x4 areg[4];          // 16 staging regs

#define STAGE_A_LOAD(KT)                                                  \
  {                                                                       \
    areg[0] = *(const f32x4*)(srcA + (KT));                               \
    areg[1] = *(const f32x4*)(srcA + (KT) + 4);                           \
    areg[2] = *(const f32x4*)(srcA + (KT) + 8);                           \
    areg[3] = *(const f32x4*)(srcA + (KT) + 12);                          \
  }
#define STAGE_A_WRITE(BUF)                                                \
  {                                                                       \
    u16x8 v0, v1;                                                         \
    _Pragma("unroll") for (int q = 0; q < 4; ++q) {                       \
      v0[q]     = (unsigned short)f2bf(areg[0][q]);                       \
      v0[4 + q] = (unsigned short)f2bf(areg[1][q]);                       \
      v1[q]     = (unsigned short)f2bf(areg[2][q]);                       \
      v1[4 + q] = (unsigned short)f2bf(areg[3][q]);                       \
    }                                                                     \
    *(u16x8*)(&As[BUF][adst0]) = v0;                                      \
    *(u16x8*)(&As[BUF][adst1]) = v1;                                      \
  }
#define STAGE_B(KT, BUF)                                                  \
  {                                                                       \
    load_lds16(bsrc[0] + (KT), &Bs[BUF][bdst[0]]);                        \
    load_lds16(bsrc[1] + (KT), &Bs[BUF][bdst[1]]);                        \
  }
#define COMPUTE(CUR)                                                      \
  {                                                                       \
    const unsigned short* Ab = &As[CUR][0];                               \
    const unsigned short* Bb = &Bs[CUR][0];                               \
    bf16x8 bf[4];                                                         \
    _Pragma("unroll") for (int nj = 0; nj < 4; ++nj)                      \
      bf[nj] = *(const bf16x8*)(Bb + bbase + nj * 512 + axx);             \
    __builtin_amdgcn_s_setprio(1);                                        \
    _Pragma("unroll") for (int mi = 0; mi < 4; ++mi) {                    \
      const bf16x8 af = *(const bf16x8*)(Ab + abase + mi * 512 + axx);    \
      _Pragma("unroll") for (int nj = 0; nj < 4; ++nj)                    \
        acc[mi][nj] = __builtin_amdgcn_mfma_f32_16x16x32_bf16(            \
            af, bf[nj], acc[mi][nj], 0, 0, 0);                            \
    }                                                                     \
    __builtin_amdgcn_s_setprio(0);                                        \
  }

  // ---- prologue: stage tile 0 into buffer 0 ----
  STAGE_A_LOAD(0);
  STAGE_B(0, 0);
  STAGE_A_WRITE(0);
  __syncthreads();

  // ---- main loop: compute cur, stage nxt; __syncthreads handles waits ----
  for (int tt = 0; tt < NT - 1; ++tt) {
    const int cur = tt & 1;
    const int ktn = (tt + 1) * BK;
    STAGE_A_LOAD(ktn);
    STAGE_B(ktn, cur ^ 1);
    COMPUTE(cur);
    STAGE_A_WRITE(cur ^ 1);
    __syncthreads();
  }
  COMPUTE((NT - 1) & 1);

  // ---- epilogue: + sign(bias); D frag: col = l&15, row = (l>>4)*4 + j ----
#pragma unroll
  for (int nj = 0; nj < 4; ++nj) {
    const int col = n0 + wn * 64 + nj * 16 + (l & 15);
    const float b  = bias[col];
    const float bs = (b > 0.f) ? 1.f : ((b < 0.f) ? -1.f : 0.f);
#pragma unroll
    for (int mi = 0; mi < 4; ++mi) {
      const int row = m0 + wm * 64 + mi * 16 + ((l >> 4) << 2);
#pragma unroll
      for (int j = 0; j < 4; ++j)
        Z[(size_t)(row + j) * N_DIM + col] = acc[mi][nj][j] + bs;
    }
  }
#undef STAGE_A_LOAD
#undef STAGE_A_WRITE
#undef STAGE_B
#undef COMPUTE
}

// ---------- slow-but-correct fallback ----------
__global__ __launch_bounds__(256) void naive_fb(
    const float* __restrict__ X, const float* __restrict__ W,
    const float* __restrict__ bias, float* __restrict__ Z) {
  const size_t id = (size_t)blockIdx.x * 256 + threadIdx.x;
  const int m = (int)(id >> 10), n = (int)(id & 1023);
  float acc = 0.f;
  for (int k = 0; k < K_DIM; ++k) {
    const float w = W[(size_t)k * N_DIM + n];
    const float s = (w > 0.f) ? 1.f : ((w < 0.f) ? -1.f : 0.f);
    acc += X[(size_t)m * K_DIM + k] * s;
  }
  const float b = bias[n];
  Z[id] = acc + ((b > 0.f) ? 1.f : ((b < 0.f) ? -1.f : 0.f));
}

extern "C" void kernel_launch(void* const* d_in, const int* in_sizes, int n_in,
                              void* d_out, int out_size, void* d_ws, size_t ws_size,
                              hipStream_t stream) {
  const float* X    = (const float*)d_in[0];
  const float* W    = (const float*)d_in[1];
  const float* bias = (const float*)d_in[2];
  float* Z = (float*)d_out;

  const size_t needW = (size_t)N_DIM * K_DIM * sizeof(unsigned short);  // 8 MiB
  if (ws_size >= needW) {
    unsigned short* WbT = (unsigned short*)d_ws;
    wsign_transpose<<<dim3((K_DIM / 64) * (N_DIM / 64)), dim3(256), 0, stream>>>(W, WbT);
    gemm_occ<<<dim3((M_DIM / BM) * (N_DIM / BN)), dim3(256), 0, stream>>>(X, WbT, bias, Z);
  } else {
    naive_fb<<<dim3((size_t)M_DIM * N_DIM / 256), dim3(256), 0, stream>>>(X, W, bias, Z);
  }
}

// Round 15
// 222.489 us; speedup vs baseline: 1.2820x; 1.2820x over previous
//
#include <hip/hip_runtime.h>

#define M_DIM 16384
#define N_DIM 1024
#define K_DIM 4096

#define BM 128
#define BN 128
#define BK 64
#define NT (K_DIM / BK)

typedef __attribute__((ext_vector_type(4))) float f32x4;
typedef __attribute__((ext_vector_type(8))) short bf16x8;
typedef __attribute__((ext_vector_type(8))) unsigned short u16x8;

static __device__ __forceinline__ short f2bf(float f) {
  union { __bf16 h; short s; } u;
  u.h = (__bf16)f;   // RNE; pairs pack into v_cvt_pk_bf16_f32
  return u.s;
}

static __device__ __forceinline__ void load_lds16(const void* g, void* l) {
  __builtin_amdgcn_global_load_lds(
      (const __attribute__((address_space(1))) void*)g,
      (__attribute__((address_space(3))) void*)l, 16, 0, 0);
}

// ---------- prepass: WbT[n][k] = bf16(sign(W[k][n])) ----------
__global__ __launch_bounds__(256) void wsign_transpose(
    const float* __restrict__ W, unsigned short* __restrict__ WbT) {
  __shared__ unsigned short tile[64][72];
  const int t  = (int)threadIdx.x;
  const int k0 = (int)(blockIdx.x >> 4) * 64;
  const int n0 = (int)(blockIdx.x & 15) * 64;
#pragma unroll
  for (int p = 0; p < 4; ++p) {
    const int r = p * 16 + (t >> 4);
    const int c = (t & 15) * 4;
    const float* src = W + (size_t)(k0 + r) * N_DIM + n0 + c;
#pragma unroll
    for (int j = 0; j < 4; ++j) {
      const float w = src[j];
      tile[r][c + j] = (w > 0.f) ? (unsigned short)0x3F80u
                                 : ((w < 0.f) ? (unsigned short)0xBF80u
                                              : (unsigned short)0u);
    }
  }
  __syncthreads();
  const int n  = t >> 2;
  const int kg = (t & 3) * 16;
  u16x8 o0, o1;
#pragma unroll
  for (int j = 0; j < 8; ++j) o0[j] = tile[kg + j][n];
#pragma unroll
  for (int j = 0; j < 8; ++j) o1[j] = tile[kg + 8 + j][n];
  unsigned short* dst = WbT + (size_t)(n0 + n) * K_DIM + k0 + kg;
  *(u16x8*)dst       = o0;
  *(u16x8*)(dst + 8) = o1;
}

// ---------- main GEMM: 128x128, BK=64, 8 waves of 64x32, 2 blocks/CU ----------
// Occupancy isolation: acc=32 VGPR, launch_bounds(512,4) -> VGPR<=128 ->
// 4 waves/SIMD; LDS 64 KiB -> 2 independent blocks/CU (16 waves/CU).
// Proven components only: BK=64 8-granule XOR swizzle (0 conflicts R1-R13),
// R9's A-staging thread pattern (fused fp32->bf16), B DMA w16 inverse-swz,
// simple 2-barrier loop, no inline asm (compiler emits counted waits).
__global__ __launch_bounds__(512, 4) void gemm_2blk(
    const float* __restrict__ X, const unsigned short* __restrict__ WbT,
    const float* __restrict__ bias, float* __restrict__ Z) {
  __shared__ __align__(16) unsigned short As[2][BM * BK];  // 32 KiB
  __shared__ __align__(16) unsigned short Bs[2][BN * BK];  // 32 KiB

  const int t   = (int)threadIdx.x;
  const int l   = t & 63;
  const int wid = t >> 6;
  const int wm  = wid >> 2;  // 0..1 -> 64-row half
  const int wn  = wid & 3;   // 0..3 -> 32-col quarter

  // XCD-bijective swizzle: 1024 blocks % 8 == 0; n-fastest within XCD
  const int bid = (int)blockIdx.x;
  const int swz = (bid & 7) * 128 + (bid >> 3);
  const int m0  = (swz >> 3) * BM;   // 128 m-tiles
  const int n0  = (swz & 7) * BN;    // 8 n-tiles

  // fragment read offsets (proven BK=64 XOR-granule swizzle)
  const int abase = (wm * 64 + (l & 15)) * BK;
  const int bbase = (wn * 32 + (l & 15)) * BK;
  const int axk0  = (((l >> 4) + 0) ^ (l & 7)) << 3;
  const int axk1  = (((l >> 4) + 4) ^ (l & 7)) << 3;

  // A staging (R9 pattern): thread -> rows {t>>3, 64+t>>3}, k-granule t&7
  const float* sA0 = X + (size_t)(m0 +  0 + (t >> 3)) * K_DIM + (t & 7) * 8;
  const float* sA1 = X + (size_t)(m0 + 64 + (t >> 3)) * K_DIM + (t & 7) * 8;
  const int adst = (t >> 3) * BK + (((t & 7) ^ ((t >> 3) & 7)) << 3);

  // B staging: linear LDS dest, inverse-swizzled global source (rule #21)
  const unsigned short* bsrc[2];
  int bdst[2];
#pragma unroll
  for (int i = 0; i < 2; ++i) {
    const int c = i * 512 + t;
    const int n = c >> 3, g = c & 7;
    bsrc[i] = WbT + (size_t)(n0 + n) * K_DIM + (g ^ (n & 7)) * 8;
    bdst[i] = c * 8;
  }

  f32x4 acc[4][2] = {};   // 32 acc regs (64x32 wave tile)
  f32x4 ar[2][2];         // 16 staging regs

#define STAGE_A_LOAD(KT)                                                  \
  {                                                                       \
    ar[0][0] = *(const f32x4*)(sA0 + (KT));                               \
    ar[0][1] = *(const f32x4*)(sA0 + (KT) + 4);                           \
    ar[1][0] = *(const f32x4*)(sA1 + (KT));                               \
    ar[1][1] = *(const f32x4*)(sA1 + (KT) + 4);                           \
  }
#define STAGE_A_WRITE(BUF)                                                \
  {                                                                       \
    _Pragma("unroll") for (int h = 0; h < 2; ++h) {                       \
      u16x8 v;                                                            \
      _Pragma("unroll") for (int q = 0; q < 4; ++q) {                     \
        v[q]     = (unsigned short)f2bf(ar[h][0][q]);                     \
        v[4 + q] = (unsigned short)f2bf(ar[h][1][q]);                     \
      }                                                                   \
      *(u16x8*)(&As[BUF][adst + h * 4096]) = v;                           \
    }                                                                     \
  }
#define STAGE_B(KT, BUF)                                                  \
  {                                                                       \
    load_lds16(bsrc[0] + (KT), &Bs[BUF][bdst[0]]);                        \
    load_lds16(bsrc[1] + (KT), &Bs[BUF][bdst[1]]);                        \
  }
#define COMPUTE(CUR)                                                      \
  {                                                                       \
    const unsigned short* Ab = &As[CUR][0];                               \
    const unsigned short* Bb = &Bs[CUR][0];                               \
    _Pragma("unroll") for (int kk = 0; kk < 2; ++kk) {                    \
      const int axk = kk ? axk1 : axk0;                                   \
      bf16x8 bf[2];                                                       \
      _Pragma("unroll") for (int nj = 0; nj < 2; ++nj)                    \
        bf[nj] = *(const bf16x8*)(Bb + bbase + nj * 1024 + axk);          \
      _Pragma("unroll") for (int mi = 0; mi < 4; ++mi) {                  \
        const bf16x8 af = *(const bf16x8*)(Ab + abase + mi * 1024 + axk); \
        _Pragma("unroll") for (int nj = 0; nj < 2; ++nj)                  \
          acc[mi][nj] = __builtin_amdgcn_mfma_f32_16x16x32_bf16(          \
              af, bf[nj], acc[mi][nj], 0, 0, 0);                          \
      }                                                                   \
    }                                                                     \
  }

  // ---- prologue: stage tile 0 into buffer 0 ----
  STAGE_A_LOAD(0);
  STAGE_B(0, 0);
  STAGE_A_WRITE(0);
  __syncthreads();

  // ---- main loop ----
  for (int tt = 0; tt < NT - 1; ++tt) {
    const int cur = tt & 1;
    const int ktn = (tt + 1) * BK;
    STAGE_A_LOAD(ktn);
    STAGE_B(ktn, cur ^ 1);
    COMPUTE(cur);
    STAGE_A_WRITE(cur ^ 1);
    __syncthreads();
  }
  COMPUTE((NT - 1) & 1);

  // ---- epilogue: + sign(bias); D frag: col = l&15, row = (l>>4)*4 + j ----
#pragma unroll
  for (int nj = 0; nj < 2; ++nj) {
    const int col = n0 + wn * 32 + nj * 16 + (l & 15);
    const float b  = bias[col];
    const float bs = (b > 0.f) ? 1.f : ((b < 0.f) ? -1.f : 0.f);
#pragma unroll
    for (int mi = 0; mi < 4; ++mi) {
      const int row = m0 + wm * 64 + mi * 16 + ((l >> 4) << 2);
#pragma unroll
      for (int j = 0; j < 4; ++j)
        Z[(size_t)(row + j) * N_DIM + col] = acc[mi][nj][j] + bs;
    }
  }
#undef STAGE_A_LOAD
#undef STAGE_A_WRITE
#undef STAGE_B
#undef COMPUTE
}

// ---------- slow-but-correct fallback ----------
__global__ __launch_bounds__(256) void naive_fb(
    const float* __restrict__ X, const float* __restrict__ W,
    const float* __restrict__ bias, float* __restrict__ Z) {
  const size_t id = (size_t)blockIdx.x * 256 + threadIdx.x;
  const int m = (int)(id >> 10), n = (int)(id & 1023);
  float acc = 0.f;
  for (int k = 0; k < K_DIM; ++k) {
    const float w = W[(size_t)k * N_DIM + n];
    const float s = (w > 0.f) ? 1.f : ((w < 0.f) ? -1.f : 0.f);
    acc += X[(size_t)m * K_DIM + k] * s;
  }
  const float b = bias[n];
  Z[id] = acc + ((b > 0.f) ? 1.f : ((b < 0.f) ? -1.f : 0.f));
}

extern "C" void kernel_launch(void* const* d_in, const int* in_sizes, int n_in,
                              void* d_out, int out_size, void* d_ws, size_t ws_size,
                              hipStream_t stream) {
  const float* X    = (const float*)d_in[0];
  const float* W    = (const float*)d_in[1];
  const float* bias = (const float*)d_in[2];
  float* Z = (float*)d_out;

  const size_t needW = (size_t)N_DIM * K_DIM * sizeof(unsigned short);  // 8 MiB
  if (ws_size >= needW) {
    unsigned short* WbT = (unsigned short*)d_ws;
    wsign_transpose<<<dim3((K_DIM / 64) * (N_DIM / 64)), dim3(256), 0, stream>>>(W, WbT);
    gemm_2blk<<<dim3((M_DIM / BM) * (N_DIM / BN)), dim3(512), 0, stream>>>(X, WbT, bias, Z);
  } else {
    naive_fb<<<dim3((size_t)M_DIM * N_DIM / 256), dim3(256), 0, stream>>>(X, W, bias, Z);
  }
}

// Round 16
// 170.859 us; speedup vs baseline: 1.6693x; 1.3022x over previous
//
#include <hip/hip_runtime.h>

#define M_DIM 16384
#define N_DIM 1024
#define K_DIM 4096

#define BM 256
#define BN 256
#define BK 64
#define NT (K_DIM / BK)

typedef __attribute__((ext_vector_type(4))) float f32x4;
typedef __attribute__((ext_vector_type(8))) short bf16x8;
typedef __attribute__((ext_vector_type(8))) unsigned short u16x8;

static __device__ __forceinline__ short f2bf(float f) {
  union { __bf16 h; short s; } u;
  u.h = (__bf16)f;   // RNE; pairs pack into v_cvt_pk_bf16_f32
  return u.s;
}

static __device__ __forceinline__ void load_lds16(const void* g, void* l) {
  __builtin_amdgcn_global_load_lds(
      (const __attribute__((address_space(1))) void*)g,
      (__attribute__((address_space(3))) void*)l, 16, 0, 0);
}

// ---------- prepass: WbT[n][k] = bf16(sign(W[k][n])) ----------
// Row stride 70 u16 (35 dwords): kg-group bank term (35*16)%32=16 -> column
// reads split across 2 bank sets, worst 2-way alias (free, m136). The old
// 72-stride had (36*16)%32=0 -> 8-way, 393K conflicts.
__global__ __launch_bounds__(256) void wsign_transpose(
    const float* __restrict__ W, unsigned short* __restrict__ WbT) {
  __shared__ unsigned short tile[64][70];
  const int t  = (int)threadIdx.x;
  const int k0 = (int)(blockIdx.x >> 4) * 64;
  const int n0 = (int)(blockIdx.x & 15) * 64;
#pragma unroll
  for (int p = 0; p < 4; ++p) {
    const int r = p * 16 + (t >> 4);
    const int c = (t & 15) * 4;
    const float* src = W + (size_t)(k0 + r) * N_DIM + n0 + c;
#pragma unroll
    for (int j = 0; j < 4; ++j) {
      const float w = src[j];
      tile[r][c + j] = (w > 0.f) ? (unsigned short)0x3F80u
                                 : ((w < 0.f) ? (unsigned short)0xBF80u
                                              : (unsigned short)0u);
    }
  }
  __syncthreads();
  const int n  = t >> 2;
  const int kg = (t & 3) * 16;
  u16x8 o0, o1;
#pragma unroll
  for (int j = 0; j < 8; ++j) o0[j] = tile[kg + j][n];
#pragma unroll
  for (int j = 0; j < 8; ++j) o1[j] = tile[kg + 8 + j][n];
  unsigned short* dst = WbT + (size_t)(n0 + n) * K_DIM + k0 + kg;
  *(u16x8*)dst       = o0;
  *(u16x8*)(dst + 8) = o1;
}

// ---------- main GEMM: R9 counted-lgkm pipeline, 1 barrier/tile ----------
// Each phase issues the NEXT quadrant's ds_reads; MFMA waits on a COUNTED
// lgkm that retires only the prior batch. The PH4 anti-overwrite barrier is
// removed (audit: t+1's writes target [cur_t], last read at t's PH3, already
// ordered by the publish barrier; t's PH4 reads only [nxt_t] + registers).
__global__ __launch_bounds__(512, 2) void gemm_r9(
    const float* __restrict__ X, const unsigned short* __restrict__ WbT,
    const float* __restrict__ bias, float* __restrict__ Z) {
  __shared__ __align__(16) unsigned short As[2][BM * BK];  // 64 KiB
  __shared__ __align__(16) unsigned short Bs[2][BN * BK];  // 64 KiB

  const int t   = (int)threadIdx.x;
  const int l   = t & 63;
  const int wid = t >> 6;
  const int wm  = wid >> 2;  // 0..1
  const int wn  = wid & 3;   // 0..3

  const int bid = (int)blockIdx.x;
  const int swz = (bid & 7) * 32 + (bid >> 3);  // bijective: 256 = 8*32
  const int m0  = (swz >> 2) * BM;
  const int n0  = (swz & 3) * BN;

  const int abase = (wm * 128 + (l & 15)) * BK;
  const int bbase = (wn * 64 + (l & 15)) * BK;
  const int axk0  = (((l >> 4) + 0) ^ (l & 7)) << 3;
  const int axk1  = (((l >> 4) + 4) ^ (l & 7)) << 3;

  // A staging: thread owns rows {i*64 + t>>3}, k-granule t&7
  const float* sA0 = X + (size_t)(m0 +   0 + (t >> 3)) * K_DIM + (t & 7) * 8;
  const float* sA1 = X + (size_t)(m0 +  64 + (t >> 3)) * K_DIM + (t & 7) * 8;
  const float* sA2 = X + (size_t)(m0 + 128 + (t >> 3)) * K_DIM + (t & 7) * 8;
  const float* sA3 = X + (size_t)(m0 + 192 + (t >> 3)) * K_DIM + (t & 7) * 8;
  const int adst = (t >> 3) * BK + (((t & 7) ^ ((t >> 3) & 7)) << 3);

  // B staging: linear LDS dest, inverse-swizzled global source
  const unsigned short* b_src[4];
  int b_dst[4];
#pragma unroll
  for (int i = 0; i < 4; ++i) {
    const int c = i * 512 + t;
    const int n = c >> 3, gp = c & 7;
    b_src[i] = WbT + (size_t)(n0 + n) * K_DIM + (gp ^ (n & 7)) * 8;
    b_dst[i] = c * 8;
  }

  f32x4 acc[8][4] = {};      // 128 acc regs
  f32x4 ar[4][2];            // A(t+1) staging (32)
  bf16x8 a0F[4], a1F[4];     // ping/pong A frags (16+16)
  bf16x8 b0F[4], b1F[4];     // kk0 / kk1 B frags (16+16)

#define SB0 __builtin_amdgcn_sched_barrier(0)
#define BAR do { SB0; __builtin_amdgcn_s_barrier(); SB0; } while (0)
#define WVM(N) do { asm volatile("s_waitcnt vmcnt(" #N ")" ::: "memory"); SB0; } while (0)
#define WLG(N) do { asm volatile("s_waitcnt lgkmcnt(" #N ")" ::: "memory"); SB0; } while (0)

#define LD_A8(KT)                                                          \
  do { SB0;                                                                \
    ar[0][0] = *(const f32x4*)(sA0 + (KT));                                \
    ar[0][1] = *(const f32x4*)(sA0 + (KT) + 4);                            \
    ar[1][0] = *(const f32x4*)(sA1 + (KT));                                \
    ar[1][1] = *(const f32x4*)(sA1 + (KT) + 4);                            \
    ar[2][0] = *(const f32x4*)(sA2 + (KT));                                \
    ar[2][1] = *(const f32x4*)(sA2 + (KT) + 4);                            \
    ar[3][0] = *(const f32x4*)(sA3 + (KT));                                \
    ar[3][1] = *(const f32x4*)(sA3 + (KT) + 4); SB0;                       \
  } while (0)
#define WR_AH(BUF, H)                                                      \
  do { SB0;                                                                \
    _Pragma("unroll") for (int j = 2 * (H); j < 2 * (H) + 2; ++j) {        \
      u16x8 v;                                                             \
      _Pragma("unroll") for (int q = 0; q < 4; ++q) {                      \
        v[q]     = (unsigned short)f2bf(ar[j][0][q]);                      \
        v[4 + q] = (unsigned short)f2bf(ar[j][1][q]);                      \
      }                                                                    \
      *(u16x8*)(&As[BUF][adst + j * 4096]) = v;                            \
    } SB0;                                                                 \
  } while (0)
#define DMA_B4(KT, BUF)                                                    \
  do { SB0;                                                                \
    _Pragma("unroll") for (int i = 0; i < 4; ++i)                          \
      load_lds16(b_src[i] + (KT), &Bs[BUF][b_dst[i]]);                     \
    SB0;                                                                   \
  } while (0)
#define RD_A(DST, KK, MIG, AB)                                             \
  do { SB0;                                                                \
    _Pragma("unroll") for (int mi = 0; mi < 4; ++mi)                       \
      DST[mi] = *(const bf16x8*)((AB) + abase + ((MIG)*4 + mi) * 1024 +    \
                                 ((KK) ? axk1 : axk0));                    \
    SB0;                                                                   \
  } while (0)
#define RD_B(DST, KK, BB)                                                  \
  do { SB0;                                                                \
    _Pragma("unroll") for (int nj = 0; nj < 4; ++nj)                       \
      DST[nj] = *(const bf16x8*)((BB) + bbase + nj * 1024 +                \
                                 ((KK) ? axk1 : axk0));                    \
    SB0;                                                                   \
  } while (0)
#define MFMA16(MIG, AF, BF)                                                \
  do { __builtin_amdgcn_s_setprio(1);                                      \
    _Pragma("unroll") for (int mi = 0; mi < 4; ++mi)                       \
      _Pragma("unroll") for (int nj = 0; nj < 4; ++nj)                     \
        acc[(MIG)*4 + mi][nj] = __builtin_amdgcn_mfma_f32_16x16x32_bf16(   \
            AF[mi], BF[nj], acc[(MIG)*4 + mi][nj], 0, 0, 0);               \
    __builtin_amdgcn_s_setprio(0);                                         \
  } while (0)

  // ---- prologue ----
  LD_A8(0);                      // A(0) x8 vm
  WVM(0);
  WR_AH(0, 0); WR_AH(0, 1);      // A(0) -> buf0 (4w)
  DMA_B4(0, 0);                  // B(0) x4 vm
  LD_A8(BK);                     // A(1) x8 vm -> [B(0):4, A(1):8]
  WVM(8);                        // retire B(0)
  WLG(0);                        // drain A(0) writes
  BAR;                           // publish buf0
  RD_A(a0F, 0, 0, As[0]);        // lgkm [a0:4]
  RD_B(b0F, 0, Bs[0]);           // lgkm [a0:4, b0:4]
  // invariant: lgkm [a0:4, b0:4]; vm [A(t+1):8]

  // ---- steady: tt = 0 .. NT-3 ----
  for (int tt = 0; tt <= NT - 3; ++tt) {
    const int cur = tt & 1, nxt = cur ^ 1;
    const unsigned short* Ab = As[cur];
    const unsigned short* Bb = Bs[cur];
    // PH1 (kk0,m0): issue a1 <- (kk0,m1); B(t+1) DMA
    RD_A(a1F, 0, 1, Ab);         // lgkm [a0:4, b0:4, a1:4]
    DMA_B4((tt + 1) * BK, nxt);  // vm [A(t+1):8, B(t+1):4]
    WLG(4);                      // retire a0,b0
    MFMA16(0, a0F, b0F);
    // PH2 (kk0,m1): issue a0 <- (kk1,m0), b1 <- kk1; A(t+1) regs -> h1
    RD_A(a0F, 1, 0, Ab);
    RD_B(b1F, 1, Bb);            // lgkm [a1:4, a0:4, b1:4]
    WVM(4);                      // retire A(t+1) x8
    WR_AH(nxt, 0);               // lgkm [a1, a0, b1, w2]
    WLG(10);                     // retire a1
    MFMA16(1, a1F, b0F);
    // PH3 (kk1,m0): write h2; issue a1 <- (kk1,m1); issue A(t+2); publish
    WR_AH(nxt, 1);               // lgkm [a0, b1, w2, w2]
    RD_A(a1F, 1, 1, Ab);         // lgkm [a0, b1, w2, w2, a1]
    LD_A8((tt + 2) * BK);        // vm [B(t+1):4, A(t+2):8]
    WVM(8);                      // retire B(t+1) (publish requirement)
    WLG(4);                      // retire a0,b1,all writes; a1 stays
    MFMA16(0, a0F, b1F);
    BAR;                         // publish nxt (sole barrier per tile)
    // PH4 (kk1,m1): issue next tile's a0,b0 from nxt; NO trailing barrier
    // (t+1's writes hit [cur_t]; its last reads were PH3, already ordered)
    RD_A(a0F, 0, 0, As[nxt]);
    RD_B(b0F, 0, Bs[nxt]);       // lgkm [a1:4, a0:4, b0:4]
    WLG(8);                      // retire a1
    MFMA16(1, a1F, b1F);
  }

  // ---- tile NT-2: steady minus LD_A8 (tail keeps both barriers) ----
  {
    const int cur = (NT - 2) & 1, nxt = cur ^ 1;
    const unsigned short* Ab = As[cur];
    const unsigned short* Bb = Bs[cur];
    RD_A(a1F, 0, 1, Ab);
    DMA_B4((NT - 1) * BK, nxt);
    WLG(4);
    MFMA16(0, a0F, b0F);
    RD_A(a0F, 1, 0, Ab);
    RD_B(b1F, 1, Bb);
    WVM(4);                      // retire A(NT-1) x8
    WR_AH(nxt, 0);
    WLG(10);
    MFMA16(1, a1F, b0F);
    WR_AH(nxt, 1);
    RD_A(a1F, 1, 1, Ab);
    WVM(0);                      // retire B(NT-1) (nothing else in flight)
    WLG(4);
    MFMA16(0, a0F, b1F);
    BAR;                         // publish
    RD_A(a0F, 0, 0, As[nxt]);
    RD_B(b0F, 0, Bs[nxt]);
    WLG(8);
    MFMA16(1, a1F, b1F);
    BAR;
  }
  // ---- tile NT-1: pure compute ----
  {
    const unsigned short* Ab = As[(NT - 1) & 1];
    const unsigned short* Bb = Bs[(NT - 1) & 1];
    RD_A(a1F, 0, 1, Ab);
    WLG(4);
    MFMA16(0, a0F, b0F);
    RD_A(a0F, 1, 0, Ab);
    RD_B(b1F, 1, Bb);
    WLG(8);
    MFMA16(1, a1F, b0F);
    RD_A(a1F, 1, 1, Ab);
    WLG(4);
    MFMA16(0, a0F, b1F);
    WLG(0);
    MFMA16(1, a1F, b1F);
  }

  // ---- epilogue: + sign(bias); D frag: col = l&15, row = (l>>4)*4 + j ----
#pragma unroll
  for (int ni = 0; ni < 4; ++ni) {
    const int col = n0 + wn * 64 + ni * 16 + (l & 15);
    const float b  = bias[col];
    const float bs = (b > 0.f) ? 1.f : ((b < 0.f) ? -1.f : 0.f);
#pragma unroll
    for (int mi = 0; mi < 8; ++mi) {
      const int row = m0 + wm * 128 + mi * 16 + ((l >> 4) << 2);
#pragma unroll
      for (int j = 0; j < 4; ++j)
        Z[(size_t)(row + j) * N_DIM + col] = acc[mi][ni][j] + bs;
    }
  }
#undef SB0
#undef BAR
#undef WVM
#undef WLG
#undef LD_A8
#undef WR_AH
#undef DMA_B4
#undef RD_A
#undef RD_B
#undef MFMA16
}

// ---------- slow-but-correct fallback ----------
__global__ __launch_bounds__(256) void naive_fb(
    const float* __restrict__ X, const float* __restrict__ W,
    const float* __restrict__ bias, float* __restrict__ Z) {
  const size_t id = (size_t)blockIdx.x * 256 + threadIdx.x;
  const int m = (int)(id >> 10), n = (int)(id & 1023);
  float acc = 0.f;
  for (int k = 0; k < K_DIM; ++k) {
    const float w = W[(size_t)k * N_DIM + n];
    const float s = (w > 0.f) ? 1.f : ((w < 0.f) ? -1.f : 0.f);
    acc += X[(size_t)m * K_DIM + k] * s;
  }
  const float b = bias[n];
  Z[id] = acc + ((b > 0.f) ? 1.f : ((b < 0.f) ? -1.f : 0.f));
}

extern "C" void kernel_launch(void* const* d_in, const int* in_sizes, int n_in,
                              void* d_out, int out_size, void* d_ws, size_t ws_size,
                              hipStream_t stream) {
  const float* X    = (const float*)d_in[0];
  const float* W    = (const float*)d_in[1];
  const float* bias = (const float*)d_in[2];
  float* Z = (float*)d_out;

  const size_t needW = (size_t)N_DIM * K_DIM * sizeof(unsigned short);  // 8 MiB
  if (ws_size >= needW) {
    unsigned short* WbT = (unsigned short*)d_ws;
    wsign_transpose<<<dim3((K_DIM / 64) * (N_DIM / 64)), dim3(256), 0, stream>>>(W, WbT);
    gemm_r9<<<dim3((M_DIM / BM) * (N_DIM / BN)), dim3(512), 0, stream>>>(X, WbT, bias, Z);
  } else {
    naive_fb<<<dim3((size_t)M_DIM * N_DIM / 256), dim3(256), 0, stream>>>(X, W, bias, Z);
  }
}